// Round 3
// baseline (297.816 us; speedup 1.0000x reference)
//
#include <hip/hip_runtime.h>
#include <hip/hip_bf16.h>

// SparseEmbedding: out[b,d] = sum_n vals[b,n] * kernel[idx[b,n], d] + bias[d]
// B=4096, NNZ=32, V=1e6, D=64, fp32.
//
// R2: one wave per row AND 1KB-per-instruction gathers.
//  - lane split: group g = lane>>4 (handles nnz n+g), slice s = lane&15
//    (float4 slice of the 64-dim row). One global_load_dwordx4 covers
//    4 random rows x 256B = 1KB -> only 8 gather instrs per row (vs 32).
//  - idx/vals preloaded once per wave (lane&31), redistributed via __shfl.
//  - cross-group reduce via __shfl_xor(16) + __shfl_xor(32).
//  - 4096 waves = 16 waves/CU; 8 independent 1KB gathers in flight per wave.

#define B_BATCH 4096
#define NNZ 32
#define DIM 64

__global__ __launch_bounds__(256) void sparse_embed_kernel(
    const int* __restrict__ idx,
    const float* __restrict__ vals,
    const float* __restrict__ kern,
    const float* __restrict__ bias,
    float* __restrict__ out)
{
    const int lane = threadIdx.x & 63;
    const int g    = lane >> 4;      // nnz sub-group 0..3
    const int s    = lane & 15;      // float4 slice of the dim
    int row = (blockIdx.x << 2) + (threadIdx.x >> 6);   // 4 waves/block
    row = __builtin_amdgcn_readfirstlane(row);

    // Preload all 32 ids/vals for this row (lane l holds entry l&31).
    const int   allid  = idx [row * NNZ + (lane & 31)];
    const float allval = vals[row * NNZ + (lane & 31)];

    float4 acc = make_float4(0.f, 0.f, 0.f, 0.f);

    #pragma unroll
    for (int n = 0; n < NNZ; n += 4) {
        const int   src = n + g;                 // uniform within each 16-lane group
        const int   id  = __shfl(allid,  src);
        const float v   = __shfl(allval, src);
        const float4 k  = *reinterpret_cast<const float4*>(
            kern + (size_t)id * DIM + s * 4);
        acc.x = fmaf(v, k.x, acc.x);
        acc.y = fmaf(v, k.y, acc.y);
        acc.z = fmaf(v, k.z, acc.z);
        acc.w = fmaf(v, k.w, acc.w);
    }

    // Reduce partial sums across the 4 groups (lanes differing in bits 4,5).
    acc.x += __shfl_xor(acc.x, 16); acc.y += __shfl_xor(acc.y, 16);
    acc.z += __shfl_xor(acc.z, 16); acc.w += __shfl_xor(acc.w, 16);
    acc.x += __shfl_xor(acc.x, 32); acc.y += __shfl_xor(acc.y, 32);
    acc.z += __shfl_xor(acc.z, 32); acc.w += __shfl_xor(acc.w, 32);

    if (lane < 16) {
        const float4 b4 = *reinterpret_cast<const float4*>(bias + s * 4);
        float4 r;
        r.x = acc.x + b4.x;
        r.y = acc.y + b4.y;
        r.z = acc.z + b4.z;
        r.w = acc.w + b4.w;
        *reinterpret_cast<float4*>(out + (size_t)row * DIM + s * 4) = r;
    }
}

extern "C" void kernel_launch(void* const* d_in, const int* in_sizes, int n_in,
                              void* d_out, int out_size, void* d_ws, size_t ws_size,
                              hipStream_t stream) {
    const int*   idx  = (const int*)  d_in[0];
    const float* vals = (const float*)d_in[1];
    const float* kern = (const float*)d_in[2];
    const float* bias = (const float*)d_in[3];
    float* out = (float*)d_out;

    const int threads = 256;          // 4 waves = 4 rows per block
    const int blocks  = B_BATCH / 4;  // 1024 blocks

    sparse_embed_kernel<<<blocks, threads, 0, stream>>>(idx, vals, kern, bias, out);
}